// Round 19
// baseline (40.786 us; speedup 1.0000x reference)
//
#include <hip/hip_runtime.h>
#include <hip/hip_bf16.h>

#define N_VOX 100000
#define C_IN  32
#define C_OUT 64
#define KOFF  27
#define CONV_T 1024            // 16 waves: 4/SIMD at 1 block/CU
#define GRID_C 256             // all CUs; tiles block-strided across blocks
#define NTILES 3125            // 100000/32 exactly (per-wave 32-voxel tiles)
#define NB_FB  782             // fallback tiles
#define WT_BLOCKS 216          // 27*64*32 / 256
#define WT_HALFS (KOFF * C_OUT * C_IN)   // 55296 bf16
#define WT_BYTES (WT_HALFS * 2)          // 110592 B

typedef __attribute__((ext_vector_type(8))) short bf16x8_t;
typedef __attribute__((ext_vector_type(4))) float f32x4_t;

__device__ __forceinline__ short f2bf(float f) {
    __hip_bfloat16 h = __float2bfloat16(f);
    return __builtin_bit_cast(short, h);
}
__device__ __forceinline__ float bf2f(unsigned short u) {
    return __builtin_bit_cast(float, (unsigned)u << 16);
}

// prep: blocks [0,216): Wt FRAGMENT-MAJOR: element (k,d,c) -> bf16 index
//   (k<<11) + ((d>>4)<<9) + (((c>>3)*16 + (d&15))<<3) + (c&7)
// so each (k, t=d>>4) B-fragment is 64 lanes' 16B chunks contiguous in lane
// order -> a wave's ds_read_b128 is a 1KB sequential read (conflict-free).
// Linear copy to LDS preserves it. blocks [216,...): feat f32->bf16 (+zero row)
__global__ void prep_kernel(const float* __restrict__ W,
                            unsigned short* __restrict__ Wt,
                            const float* __restrict__ feat,
                            unsigned short* __restrict__ fb) {
    int bid = blockIdx.x;
    if (bid < WT_BLOCKS) {
        int i = bid * 256 + threadIdx.x;   // exactly 55296
        int c = i & 31;
        int d = (i >> 5) & 63;
        int k = i >> 11;
        int dst = (k << 11) + ((d >> 4) << 9) + ((((c >> 3) << 4) + (d & 15)) << 3) + (c & 7);
        Wt[dst] = (unsigned short)f2bf(W[k * (C_IN * C_OUT) + c * C_OUT + d]);
    } else {
        int t = (bid - WT_BLOCKS) * 256 + threadIdx.x;
        const int total8 = ((N_VOX + 1) * C_IN) / 8;    // 400004
        if (t >= total8) return;
        int e = t * 8;
        bf16x8_t o;
        if (e < N_VOX * C_IN) {
            const f32x4_t* fp = (const f32x4_t*)(feat + e);
            f32x4_t f0 = fp[0], f1 = fp[1];
            o[0] = f2bf(f0[0]); o[1] = f2bf(f0[1]); o[2] = f2bf(f0[2]); o[3] = f2bf(f0[3]);
            o[4] = f2bf(f1[0]); o[5] = f2bf(f1[1]); o[6] = f2bf(f1[2]); o[7] = f2bf(f1[3]);
        } else {
            o = (bf16x8_t)(short)0;
        }
        *(bf16x8_t*)(fb + e) = o;
    }
}

#define GLOAD(dst, voff)                                                      \
    asm volatile("global_load_dwordx4 %0, %1, %2"                             \
                 : "=v"(dst) : "v"(voff), "s"(feat_bf))

#define VMW(n) do {                                                           \
    asm volatile("s_waitcnt vmcnt(" #n ")" ::: "memory");                     \
    __builtin_amdgcn_sched_barrier(0);                                        \
} while (0)

template <bool OUTBF>
__global__ __attribute__((amdgpu_flat_work_group_size(CONV_T, CONV_T),
                          amdgpu_waves_per_eu(4, 4)))
void conv_kernel(
    const unsigned short* __restrict__ feat_bf,
    const int* __restrict__ nidx,
    const unsigned short* __restrict__ WtG,
    float* __restrict__ outf, unsigned short* __restrict__ outb,
    float* __restrict__ partials)
{
    __shared__ unsigned short wt_lds[WT_HALFS];   // 110592 B, fragment-major
    __shared__ float lsum[16][C_OUT];
    __shared__ float lsq[16][C_OUT];

    const int tid  = threadIdx.x;
    const int wid  = tid >> 6;
    const int lane = tid & 63;
    const int colr = lane & 15;
    const int kch  = lane >> 4;

    // stage weights once per block (linear copy preserves fragment layout)
    for (int j = tid; j < WT_HALFS / 8; j += CONV_T)
        ((bf16x8_t*)wt_lds)[j] = ((const bf16x8_t*)WtG)[j];
    __syncthreads();

    const int b = blockIdx.x;
    // block-strided per-wave tile id: every CU gets ~12.2 active waves
    const int g = wid * GRID_C + b;
    const bool active = (g < NTILES);
    const int base = g * 32;

    float psum[4] = {0.f, 0.f, 0.f, 0.f};
    float psq[4]  = {0.f, 0.f, 0.f, 0.f};

    if (active) {
        // phase 0: 54 gather byte-offsets (compiler nidx VMEM drains here;
        // the staging __syncthreads drained vmcnt -> counting starts clean)
        unsigned off[54];
        #pragma unroll
        for (int m = 0; m < 2; ++m) {
            int vx = base + m * 16 + colr;
            bool val = vx < N_VOX;
            const int* nr = nidx + (val ? vx : 0) * KOFF;
            int force = val ? 0 : -1;
            #pragma unroll
            for (int k = 0; k < KOFF; ++k) {
                int id = nr[k] | force;
                int s = (id < 0) ? N_VOX : id;    // zero row for invalid
                off[k * 2 + m] = ((unsigned)s << 6) + (unsigned)(kch << 4);
            }
        }
        __builtin_amdgcn_sched_barrier(0);

        f32x4_t acc0[4], acc1[4];
        #pragma unroll
        for (int t = 0; t < 4; ++t) { acc0[t] = (f32x4_t)0.0f; acc1[t] = (f32x4_t)0.0f; }

        // 2-chunk-deep burst: 12 fragments live (round-13-proven ping-pong)
        bf16x8_t a[12];
        #pragma unroll
        for (int u = 0; u < 12; ++u) GLOAD(a[u], off[u]);
        __builtin_amdgcn_sched_barrier(0);

        // 9 chunks of 3 k-offsets; each b-read feeds TWO MFMAs (M=32)
        #pragma unroll
        for (int c = 0; c < 9; ++c) {
            if (c < 8) { VMW(6); } else { VMW(0); }
            const int ab = (c & 1) * 6;
            #pragma unroll
            for (int j = 0; j < 3; ++j) {
                const int kk = c * 3 + j;
                #pragma unroll
                for (int t = 0; t < 4; ++t) {
                    // fragment-major: 1KB contiguous, lane-ordered -> no conflicts
                    int o = (kk << 12) + (t << 10) + (lane << 4);
                    bf16x8_t bb = *(const bf16x8_t*)((const char*)wt_lds + o);
                    acc0[t] = __builtin_amdgcn_mfma_f32_16x16x32_bf16(
                        a[ab + j * 2 + 0], bb, acc0[t], 0, 0, 0);
                    acc1[t] = __builtin_amdgcn_mfma_f32_16x16x32_bf16(
                        a[ab + j * 2 + 1], bb, acc1[t], 0, 0, 0);
                }
            }
            if (c + 2 < 9) {
                const int nb2 = ((c + 2) & 1) * 6;
                #pragma unroll
                for (int u = 0; u < 6; ++u) GLOAD(a[nb2 + u], off[(c + 2) * 6 + u]);
                __builtin_amdgcn_sched_barrier(0);
            }
        }

        // epilogue: C/D col = lane&15 (channel), row = kch*4+i (voxel)
        #pragma unroll
        for (int t = 0; t < 4; ++t) {
            #pragma unroll
            for (int i = 0; i < 4; ++i) {
                int v0 = base + kch * 4 + i;
                int v1 = v0 + 16;
                int ch = t * 16 + colr;
                float x0 = acc0[t][i], x1 = acc1[t][i];
                if (v0 < N_VOX) {
                    if constexpr (OUTBF) outb[v0 * C_OUT + ch] = (unsigned short)f2bf(x0);
                    else                 outf[v0 * C_OUT + ch] = x0;
                }
                if (v1 < N_VOX) {
                    if constexpr (OUTBF) outb[v1 * C_OUT + ch] = (unsigned short)f2bf(x1);
                    else                 outf[v1 * C_OUT + ch] = x1;
                }
                psum[t] += x0 + x1;
                psq[t]  += x0 * x0 + x1 * x1;
            }
        }
    }

    #pragma unroll
    for (int t = 0; t < 4; ++t) {
        psum[t] += __shfl_xor(psum[t], 16);
        psum[t] += __shfl_xor(psum[t], 32);
        psq[t]  += __shfl_xor(psq[t], 16);
        psq[t]  += __shfl_xor(psq[t], 32);
    }
    if (lane < 16) {
        #pragma unroll
        for (int t = 0; t < 4; ++t) {
            lsum[wid][t * 16 + lane] = psum[t];
            lsq[wid][t * 16 + lane]  = psq[t];
        }
    }
    __syncthreads();
    if (tid < 128) {
        int c = tid & 63;
        float s = 0.f;
        if (tid < 64) {
            #pragma unroll
            for (int w = 0; w < 16; ++w) s += lsum[w][c];
        } else {
            #pragma unroll
            for (int w = 0; w < 16; ++w) s += lsq[w][c];
        }
        partials[tid * GRID_C + b] = s;
    }
}

// fallback (tiny ws): f32 gather, shallow loop, M=16, non-persistent
__global__ __launch_bounds__(512) void conv_fb_kernel(
    const float* __restrict__ feat,
    const int* __restrict__ nidx,
    const unsigned short* __restrict__ WtG,
    float* __restrict__ outf, float* __restrict__ partials)
{
    __shared__ unsigned short wt_lds[WT_HALFS];
    __shared__ float lsum[8][C_OUT];
    __shared__ float lsq[8][C_OUT];

    const int tid  = threadIdx.x;
    const int wid  = tid >> 6;
    const int lane = tid & 63;
    const int colr = lane & 15;
    const int kch  = lane >> 4;
    const int base = blockIdx.x * 128 + wid * 16;
    const int vox  = base + colr;
    const bool valid = (vox < N_VOX);
    const int* nrow = nidx + (valid ? vox : 0) * KOFF;

    for (int j = tid; j < WT_HALFS / 8; j += 512)
        ((bf16x8_t*)wt_lds)[j] = ((const bf16x8_t*)WtG)[j];
    __syncthreads();

    f32x4_t acc[4];
    #pragma unroll
    for (int t = 0; t < 4; ++t) acc[t] = (f32x4_t)0.0f;

    for (int k = 0; k < KOFF; ++k) {
        int idx = valid ? nrow[k] : -1;
        bf16x8_t av = (bf16x8_t)(short)0;
        if (idx >= 0) {
            const f32x4_t* fp = (const f32x4_t*)(feat + (idx << 5) + kch * 8);
            f32x4_t f0 = fp[0], f1 = fp[1];
            av[0] = f2bf(f0[0]); av[1] = f2bf(f0[1]);
            av[2] = f2bf(f0[2]); av[3] = f2bf(f0[3]);
            av[4] = f2bf(f1[0]); av[5] = f2bf(f1[1]);
            av[6] = f2bf(f1[2]); av[7] = f2bf(f1[3]);
        }
        #pragma unroll
        for (int t = 0; t < 4; ++t) {
            int o = (k << 12) + (t << 10) + (lane << 4);   // fragment-major
            bf16x8_t bb = *(const bf16x8_t*)((const char*)wt_lds + o);
            acc[t] = __builtin_amdgcn_mfma_f32_16x16x32_bf16(av, bb, acc[t], 0, 0, 0);
        }
    }

    float psum[4], psq[4];
    #pragma unroll
    for (int t = 0; t < 4; ++t) { psum[t] = 0.f; psq[t] = 0.f; }
    #pragma unroll
    for (int t = 0; t < 4; ++t) {
        #pragma unroll
        for (int i = 0; i < 4; ++i) {
            int v = base + kch * 4 + i;
            float x = acc[t][i];
            if (v < N_VOX) outf[v * C_OUT + t * 16 + colr] = x;
            psum[t] += x;
            psq[t]  += x * x;
        }
    }
    #pragma unroll
    for (int t = 0; t < 4; ++t) {
        psum[t] += __shfl_xor(psum[t], 16);
        psum[t] += __shfl_xor(psum[t], 32);
        psq[t]  += __shfl_xor(psq[t], 16);
        psq[t]  += __shfl_xor(psq[t], 32);
    }
    if (lane < 16) {
        #pragma unroll
        for (int t = 0; t < 4; ++t) {
            lsum[wid][t * 16 + lane] = psum[t];
            lsq[wid][t * 16 + lane]  = psq[t];
        }
    }
    __syncthreads();
    if (tid < 128) {
        int c = tid & 63;
        float s = 0.f;
        if (tid < 64) {
            #pragma unroll
            for (int w = 0; w < 8; ++w) s += lsum[w][c];
        } else {
            #pragma unroll
            for (int w = 0; w < 8; ++w) s += lsq[w][c];
        }
        partials[tid * NB_FB + blockIdx.x] = s;
    }
}

__global__ __launch_bounds__(256) void stats_kernel(
    const float* __restrict__ partials, int nb,
    const float* __restrict__ gamma, const float* __restrict__ beta,
    float* __restrict__ ss)
{
    __shared__ float bs[4], bq[4];
    const int c = blockIdx.x;
    const float* ps = partials + c * nb;
    const float* pq = partials + (64 + c) * nb;
    float s = 0.f, q = 0.f;
    for (int i = threadIdx.x; i < nb; i += 256) {
        s += ps[i];
        q += pq[i];
    }
    #pragma unroll
    for (int o = 1; o < 64; o <<= 1) {
        s += __shfl_xor(s, o);
        q += __shfl_xor(q, o);
    }
    int wid = threadIdx.x >> 6, lane = threadIdx.x & 63;
    if (lane == 0) { bs[wid] = s; bq[wid] = q; }
    __syncthreads();
    if (threadIdx.x == 0) {
        float S = bs[0] + bs[1] + bs[2] + bs[3];
        float Q = bq[0] + bq[1] + bq[2] + bq[3];
        float mean = S * (1.0f / N_VOX);
        float var  = Q * (1.0f / N_VOX) - mean * mean;
        float inv  = rsqrtf(var + 1e-5f);
        float sc   = gamma[c] * inv;
        ss[c]      = sc;
        ss[64 + c] = beta[c] - mean * sc;
    }
}

// bf16 intermediate -> f32 output
__global__ void bn_relu_b_kernel(const unsigned short* __restrict__ cbf,
                                 const float* __restrict__ ss,
                                 float* __restrict__ out) {
    int i = blockIdx.x * 256 + threadIdx.x;   // exactly N*64/8 threads
    bf16x8_t v = ((const bf16x8_t*)cbf)[i];
    int d0 = (i * 8) & 63;
    f32x4_t sc0 = *(const f32x4_t*)(ss + d0);
    f32x4_t sc1 = *(const f32x4_t*)(ss + d0 + 4);
    f32x4_t sh0 = *(const f32x4_t*)(ss + 64 + d0);
    f32x4_t sh1 = *(const f32x4_t*)(ss + 64 + d0 + 4);
    f32x4_t o0, o1;
    #pragma unroll
    for (int j = 0; j < 4; ++j) {
        o0[j] = fmaxf(bf2f((unsigned short)v[j]) * sc0[j] + sh0[j], 0.f);
        o1[j] = fmaxf(bf2f((unsigned short)v[j + 4]) * sc1[j] + sh1[j], 0.f);
    }
    ((f32x4_t*)out)[2 * i]     = o0;
    ((f32x4_t*)out)[2 * i + 1] = o1;
}

// f32 in-place
__global__ void bn_relu_f_kernel(float* __restrict__ out,
                                 const float* __restrict__ ss) {
    int i = blockIdx.x * 256 + threadIdx.x;  // exactly N*64/4 threads
    f32x4_t v = ((f32x4_t*)out)[i];
    int d0 = (i * 4) & 63;
    f32x4_t sc = *(const f32x4_t*)(ss + d0);
    f32x4_t sh = *(const f32x4_t*)(ss + 64 + d0);
    #pragma unroll
    for (int j = 0; j < 4; ++j) v[j] = fmaxf(v[j] * sc[j] + sh[j], 0.f);
    ((f32x4_t*)out)[i] = v;
}

extern "C" void kernel_launch(void* const* d_in, const int* in_sizes, int n_in,
                              void* d_out, int out_size, void* d_ws, size_t ws_size,
                              hipStream_t stream) {
    const float* feat  = (const float*)d_in[0];
    const int*   nidx  = (const int*)d_in[1];
    const float* W     = (const float*)d_in[2];
    const float* gamma = (const float*)d_in[3];
    const float* beta  = (const float*)d_in[4];
    float* out = (float*)d_out;

    char* ws = (char*)d_ws;
    const size_t wt_bytes  = WT_BYTES;                         // 110592
    const size_t fb_bytes  = (size_t)(N_VOX + 1) * C_IN * 2;   // 6400064
    const size_t cb_bytes  = (size_t)N_VOX * C_OUT * 2;        // 12800000
    const size_t pt_bytes  = (size_t)128 * NB_FB * 4;          // 400384 (covers both)

    const bool bf_ok = ws_size >= wt_bytes + fb_bytes + pt_bytes + 1024;
    const bool cb_ok = ws_size >= wt_bytes + fb_bytes + cb_bytes + pt_bytes + 1024;

    unsigned short* Wt = (unsigned short*)ws;
    unsigned short* feat_bf = (unsigned short*)(ws + wt_bytes);
    unsigned short* cbf = (unsigned short*)(ws + wt_bytes + fb_bytes);
    float* partials;
    if (cb_ok)       partials = (float*)(ws + wt_bytes + fb_bytes + cb_bytes);
    else if (bf_ok)  partials = (float*)(ws + wt_bytes + fb_bytes);
    else             partials = (float*)(ws + wt_bytes);
    float* ss = partials + 128 * NB_FB;

    if (bf_ok) {
        int feat_blocks = (((N_VOX + 1) * C_IN) / 8 + 255) / 256;  // 1563
        prep_kernel<<<WT_BLOCKS + feat_blocks, 256, 0, stream>>>(W, Wt, feat, feat_bf);
        if (cb_ok)
            conv_kernel<true><<<GRID_C, CONV_T, 0, stream>>>(
                feat_bf, nidx, Wt, out, cbf, partials);
        else
            conv_kernel<false><<<GRID_C, CONV_T, 0, stream>>>(
                feat_bf, nidx, Wt, out, cbf, partials);
        stats_kernel<<<C_OUT, 256, 0, stream>>>(partials, GRID_C, gamma, beta, ss);
    } else {
        prep_kernel<<<WT_BLOCKS, 256, 0, stream>>>(W, Wt, feat, Wt);
        conv_fb_kernel<<<NB_FB, 512, 0, stream>>>(feat, nidx, Wt, out, partials);
        stats_kernel<<<C_OUT, 256, 0, stream>>>(partials, NB_FB, gamma, beta, ss);
    }
    if (cb_ok)
        bn_relu_b_kernel<<<N_VOX * C_OUT / 8 / 256, 256, 0, stream>>>(cbf, ss, out);
    else
        bn_relu_f_kernel<<<N_VOX * C_OUT / 4 / 256, 256, 0, stream>>>(out, ss);
}

// Round 20
// 39.118 us; speedup vs baseline: 1.0427x; 1.0427x over previous
//
#include <hip/hip_runtime.h>
#include <hip/hip_bf16.h>

#define N_VOX 100000
#define C_IN  32
#define C_OUT 64
#define KOFF  27
#define CONV_T 1024            // 16 waves: 4/SIMD at 1 block/CU
#define GRID_C 256             // all CUs; tiles block-strided across blocks
#define NTILES 3125            // 100000/32 exactly (per-wave 32-voxel tiles)
#define NB_FB  782             // fallback tiles
#define WT_BLOCKS 216          // 27*64*32 / 256
#define WT_HALFS (KOFF * C_OUT * C_IN)   // 55296 bf16
#define WT_BYTES (WT_HALFS * 2)          // 110592 B

typedef __attribute__((ext_vector_type(8))) short bf16x8_t;
typedef __attribute__((ext_vector_type(4))) float f32x4_t;

__device__ __forceinline__ short f2bf(float f) {
    __hip_bfloat16 h = __float2bfloat16(f);
    return __builtin_bit_cast(short, h);
}
__device__ __forceinline__ float bf2f(unsigned short u) {
    return __builtin_bit_cast(float, (unsigned)u << 16);
}

// prep: blocks [0,216): Wt PRE-SWIZZLED: element (k,d,c) -> linear index
// (k<<11|d<<5|c) ^ ((d&7)<<3); linear copy to LDS preserves the bank swizzle.
// blocks [216,...): features f32 -> bf16 (+ zero row at N_VOX)
__global__ void prep_kernel(const float* __restrict__ W,
                            unsigned short* __restrict__ Wt,
                            const float* __restrict__ feat,
                            unsigned short* __restrict__ fb) {
    int bid = blockIdx.x;
    if (bid < WT_BLOCKS) {
        int i = bid * 256 + threadIdx.x;   // exactly 55296
        int c = i & 31;
        int d = (i >> 5) & 63;
        int k = i >> 11;
        int dst = i ^ ((d & 7) << 3);
        Wt[dst] = (unsigned short)f2bf(W[k * (C_IN * C_OUT) + c * C_OUT + d]);
    } else {
        int t = (bid - WT_BLOCKS) * 256 + threadIdx.x;
        const int total8 = ((N_VOX + 1) * C_IN) / 8;    // 400004
        if (t >= total8) return;
        int e = t * 8;
        bf16x8_t o;
        if (e < N_VOX * C_IN) {
            const f32x4_t* fp = (const f32x4_t*)(feat + e);
            f32x4_t f0 = fp[0], f1 = fp[1];
            o[0] = f2bf(f0[0]); o[1] = f2bf(f0[1]); o[2] = f2bf(f0[2]); o[3] = f2bf(f0[3]);
            o[4] = f2bf(f1[0]); o[5] = f2bf(f1[1]); o[6] = f2bf(f1[2]); o[7] = f2bf(f1[3]);
        } else {
            o = (bf16x8_t)(short)0;
        }
        *(bf16x8_t*)(fb + e) = o;
    }
}

#define GLOAD(dst, voff)                                                      \
    asm volatile("global_load_dwordx4 %0, %1, %2"                             \
                 : "=v"(dst) : "v"(voff), "s"(feat_bf))

#define VMW(n) do {                                                           \
    asm volatile("s_waitcnt vmcnt(" #n ")" ::: "memory");                     \
    __builtin_amdgcn_sched_barrier(0);                                        \
} while (0)

template <bool OUTBF>
__global__ __attribute__((amdgpu_flat_work_group_size(CONV_T, CONV_T),
                          amdgpu_waves_per_eu(4, 4)))
void conv_kernel(
    const unsigned short* __restrict__ feat_bf,
    const int* __restrict__ nidx,
    const unsigned short* __restrict__ WtG,
    float* __restrict__ outf, unsigned short* __restrict__ outb,
    float* __restrict__ partials)
{
    __shared__ unsigned short wt_lds[WT_HALFS];   // 110592 B, swizzle pre-baked
    __shared__ float lsum[16][C_OUT];
    __shared__ float lsq[16][C_OUT];

    const int tid  = threadIdx.x;
    const int wid  = tid >> 6;
    const int lane = tid & 63;
    const int colr = lane & 15;
    const int kch  = lane >> 4;

    // stage weights once per block
    for (int j = tid; j < WT_HALFS / 8; j += CONV_T)
        ((bf16x8_t*)wt_lds)[j] = ((const bf16x8_t*)WtG)[j];
    __syncthreads();

    const int b = blockIdx.x;
    // block-strided per-wave tile id: every CU gets ~12.2 active waves
    const int g = wid * GRID_C + b;
    const bool active = (g < NTILES);
    const int base = g * 32;

    float psum[4] = {0.f, 0.f, 0.f, 0.f};
    float psq[4]  = {0.f, 0.f, 0.f, 0.f};

    if (active) {
        // phase 0: 54 gather byte-offsets (compiler nidx VMEM drains here;
        // the staging __syncthreads drained vmcnt -> counting starts clean)
        unsigned off[54];
        #pragma unroll
        for (int m = 0; m < 2; ++m) {
            int vx = base + m * 16 + colr;
            bool val = vx < N_VOX;
            const int* nr = nidx + (val ? vx : 0) * KOFF;
            int force = val ? 0 : -1;
            #pragma unroll
            for (int k = 0; k < KOFF; ++k) {
                int id = nr[k] | force;
                int s = (id < 0) ? N_VOX : id;    // zero row for invalid
                off[k * 2 + m] = ((unsigned)s << 6) + (unsigned)(kch << 4);
            }
        }
        __builtin_amdgcn_sched_barrier(0);

        f32x4_t acc0[4], acc1[4];
        #pragma unroll
        for (int t = 0; t < 4; ++t) { acc0[t] = (f32x4_t)0.0f; acc1[t] = (f32x4_t)0.0f; }

        // 2-chunk-deep burst: 12 fragments live (round-13-proven ping-pong)
        bf16x8_t a[12];
        #pragma unroll
        for (int u = 0; u < 12; ++u) GLOAD(a[u], off[u]);
        __builtin_amdgcn_sched_barrier(0);

        // 9 chunks of 3 k-offsets; each b-read feeds TWO MFMAs (M=32)
        #pragma unroll
        for (int c = 0; c < 9; ++c) {
            if (c < 8) { VMW(6); } else { VMW(0); }
            const int ab = (c & 1) * 6;
            #pragma unroll
            for (int j = 0; j < 3; ++j) {
                const int kk = c * 3 + j;
                #pragma unroll
                for (int t = 0; t < 4; ++t) {
                    const int rw = t * 16 + colr;
                    int o = (kk << 12) + (rw << 6) + (kch << 4);
                    o ^= (rw & 7) << 4;
                    bf16x8_t bb = *(const bf16x8_t*)((const char*)wt_lds + o);
                    acc0[t] = __builtin_amdgcn_mfma_f32_16x16x32_bf16(
                        a[ab + j * 2 + 0], bb, acc0[t], 0, 0, 0);
                    acc1[t] = __builtin_amdgcn_mfma_f32_16x16x32_bf16(
                        a[ab + j * 2 + 1], bb, acc1[t], 0, 0, 0);
                }
            }
            if (c + 2 < 9) {
                const int nb2 = ((c + 2) & 1) * 6;
                #pragma unroll
                for (int u = 0; u < 6; ++u) GLOAD(a[nb2 + u], off[(c + 2) * 6 + u]);
                __builtin_amdgcn_sched_barrier(0);
            }
        }

        // epilogue: C/D col = lane&15 (channel), row = kch*4+i (voxel)
        #pragma unroll
        for (int t = 0; t < 4; ++t) {
            #pragma unroll
            for (int i = 0; i < 4; ++i) {
                int v0 = base + kch * 4 + i;
                int v1 = v0 + 16;
                int ch = t * 16 + colr;
                float x0 = acc0[t][i], x1 = acc1[t][i];
                if (v0 < N_VOX) {
                    if constexpr (OUTBF) outb[v0 * C_OUT + ch] = (unsigned short)f2bf(x0);
                    else                 outf[v0 * C_OUT + ch] = x0;
                }
                if (v1 < N_VOX) {
                    if constexpr (OUTBF) outb[v1 * C_OUT + ch] = (unsigned short)f2bf(x1);
                    else                 outf[v1 * C_OUT + ch] = x1;
                }
                psum[t] += x0 + x1;
                psq[t]  += x0 * x0 + x1 * x1;
            }
        }
    }

    #pragma unroll
    for (int t = 0; t < 4; ++t) {
        psum[t] += __shfl_xor(psum[t], 16);
        psum[t] += __shfl_xor(psum[t], 32);
        psq[t]  += __shfl_xor(psq[t], 16);
        psq[t]  += __shfl_xor(psq[t], 32);
    }
    if (lane < 16) {
        #pragma unroll
        for (int t = 0; t < 4; ++t) {
            lsum[wid][t * 16 + lane] = psum[t];
            lsq[wid][t * 16 + lane]  = psq[t];
        }
    }
    __syncthreads();
    if (tid < 128) {
        int c = tid & 63;
        float s = 0.f;
        if (tid < 64) {
            #pragma unroll
            for (int w = 0; w < 16; ++w) s += lsum[w][c];
        } else {
            #pragma unroll
            for (int w = 0; w < 16; ++w) s += lsq[w][c];
        }
        partials[tid * GRID_C + b] = s;
    }
}

// fallback (tiny ws): f32 gather, shallow loop, M=16, non-persistent
__global__ __launch_bounds__(512) void conv_fb_kernel(
    const float* __restrict__ feat,
    const int* __restrict__ nidx,
    const unsigned short* __restrict__ WtG,
    float* __restrict__ outf, float* __restrict__ partials)
{
    __shared__ unsigned short wt_lds[WT_HALFS];
    __shared__ float lsum[8][C_OUT];
    __shared__ float lsq[8][C_OUT];

    const int tid  = threadIdx.x;
    const int wid  = tid >> 6;
    const int lane = tid & 63;
    const int colr = lane & 15;
    const int kch  = lane >> 4;
    const int base = blockIdx.x * 128 + wid * 16;
    const int vox  = base + colr;
    const bool valid = (vox < N_VOX);
    const int* nrow = nidx + (valid ? vox : 0) * KOFF;

    for (int j = tid; j < WT_HALFS / 8; j += 512)
        ((bf16x8_t*)wt_lds)[j] = ((const bf16x8_t*)WtG)[j];
    __syncthreads();

    f32x4_t acc[4];
    #pragma unroll
    for (int t = 0; t < 4; ++t) acc[t] = (f32x4_t)0.0f;

    for (int k = 0; k < KOFF; ++k) {
        int idx = valid ? nrow[k] : -1;
        bf16x8_t av = (bf16x8_t)(short)0;
        if (idx >= 0) {
            const f32x4_t* fp = (const f32x4_t*)(feat + (idx << 5) + kch * 8);
            f32x4_t f0 = fp[0], f1 = fp[1];
            av[0] = f2bf(f0[0]); av[1] = f2bf(f0[1]);
            av[2] = f2bf(f0[2]); av[3] = f2bf(f0[3]);
            av[4] = f2bf(f1[0]); av[5] = f2bf(f1[1]);
            av[6] = f2bf(f1[2]); av[7] = f2bf(f1[3]);
        }
        #pragma unroll
        for (int t = 0; t < 4; ++t) {
            int rw = t * 16 + colr;
            int o = (k << 12) + (rw << 6) + (kch << 4);
            o ^= (rw & 7) << 4;
            bf16x8_t bb = *(const bf16x8_t*)((const char*)wt_lds + o);
            acc[t] = __builtin_amdgcn_mfma_f32_16x16x32_bf16(av, bb, acc[t], 0, 0, 0);
        }
    }

    float psum[4], psq[4];
    #pragma unroll
    for (int t = 0; t < 4; ++t) { psum[t] = 0.f; psq[t] = 0.f; }
    #pragma unroll
    for (int t = 0; t < 4; ++t) {
        #pragma unroll
        for (int i = 0; i < 4; ++i) {
            int v = base + kch * 4 + i;
            float x = acc[t][i];
            if (v < N_VOX) outf[v * C_OUT + t * 16 + colr] = x;
            psum[t] += x;
            psq[t]  += x * x;
        }
    }
    #pragma unroll
    for (int t = 0; t < 4; ++t) {
        psum[t] += __shfl_xor(psum[t], 16);
        psum[t] += __shfl_xor(psum[t], 32);
        psq[t]  += __shfl_xor(psq[t], 16);
        psq[t]  += __shfl_xor(psq[t], 32);
    }
    if (lane < 16) {
        #pragma unroll
        for (int t = 0; t < 4; ++t) {
            lsum[wid][t * 16 + lane] = psum[t];
            lsq[wid][t * 16 + lane]  = psq[t];
        }
    }
    __syncthreads();
    if (tid < 128) {
        int c = tid & 63;
        float s = 0.f;
        if (tid < 64) {
            #pragma unroll
            for (int w = 0; w < 8; ++w) s += lsum[w][c];
        } else {
            #pragma unroll
            for (int w = 0; w < 8; ++w) s += lsq[w][c];
        }
        partials[tid * NB_FB + blockIdx.x] = s;
    }
}

__global__ __launch_bounds__(256) void stats_kernel(
    const float* __restrict__ partials, int nb,
    const float* __restrict__ gamma, const float* __restrict__ beta,
    float* __restrict__ ss)
{
    __shared__ float bs[4], bq[4];
    const int c = blockIdx.x;
    const float* ps = partials + c * nb;
    const float* pq = partials + (64 + c) * nb;
    float s = 0.f, q = 0.f;
    for (int i = threadIdx.x; i < nb; i += 256) {
        s += ps[i];
        q += pq[i];
    }
    #pragma unroll
    for (int o = 1; o < 64; o <<= 1) {
        s += __shfl_xor(s, o);
        q += __shfl_xor(q, o);
    }
    int wid = threadIdx.x >> 6, lane = threadIdx.x & 63;
    if (lane == 0) { bs[wid] = s; bq[wid] = q; }
    __syncthreads();
    if (threadIdx.x == 0) {
        float S = bs[0] + bs[1] + bs[2] + bs[3];
        float Q = bq[0] + bq[1] + bq[2] + bq[3];
        float mean = S * (1.0f / N_VOX);
        float var  = Q * (1.0f / N_VOX) - mean * mean;
        float inv  = rsqrtf(var + 1e-5f);
        float sc   = gamma[c] * inv;
        ss[c]      = sc;
        ss[64 + c] = beta[c] - mean * sc;
    }
}

// bf16 intermediate -> f32 output
__global__ void bn_relu_b_kernel(const unsigned short* __restrict__ cbf,
                                 const float* __restrict__ ss,
                                 float* __restrict__ out) {
    int i = blockIdx.x * 256 + threadIdx.x;   // exactly N*64/8 threads
    bf16x8_t v = ((const bf16x8_t*)cbf)[i];
    int d0 = (i * 8) & 63;
    f32x4_t sc0 = *(const f32x4_t*)(ss + d0);
    f32x4_t sc1 = *(const f32x4_t*)(ss + d0 + 4);
    f32x4_t sh0 = *(const f32x4_t*)(ss + 64 + d0);
    f32x4_t sh1 = *(const f32x4_t*)(ss + 64 + d0 + 4);
    f32x4_t o0, o1;
    #pragma unroll
    for (int j = 0; j < 4; ++j) {
        o0[j] = fmaxf(bf2f((unsigned short)v[j]) * sc0[j] + sh0[j], 0.f);
        o1[j] = fmaxf(bf2f((unsigned short)v[j + 4]) * sc1[j] + sh1[j], 0.f);
    }
    ((f32x4_t*)out)[2 * i]     = o0;
    ((f32x4_t*)out)[2 * i + 1] = o1;
}

// f32 in-place
__global__ void bn_relu_f_kernel(float* __restrict__ out,
                                 const float* __restrict__ ss) {
    int i = blockIdx.x * 256 + threadIdx.x;  // exactly N*64/4 threads
    f32x4_t v = ((f32x4_t*)out)[i];
    int d0 = (i * 4) & 63;
    f32x4_t sc = *(const f32x4_t*)(ss + d0);
    f32x4_t sh = *(const f32x4_t*)(ss + 64 + d0);
    #pragma unroll
    for (int j = 0; j < 4; ++j) v[j] = fmaxf(v[j] * sc[j] + sh[j], 0.f);
    ((f32x4_t*)out)[i] = v;
}

extern "C" void kernel_launch(void* const* d_in, const int* in_sizes, int n_in,
                              void* d_out, int out_size, void* d_ws, size_t ws_size,
                              hipStream_t stream) {
    const float* feat  = (const float*)d_in[0];
    const int*   nidx  = (const int*)d_in[1];
    const float* W     = (const float*)d_in[2];
    const float* gamma = (const float*)d_in[3];
    const float* beta  = (const float*)d_in[4];
    float* out = (float*)d_out;

    char* ws = (char*)d_ws;
    const size_t wt_bytes  = WT_BYTES;                         // 110592
    const size_t fb_bytes  = (size_t)(N_VOX + 1) * C_IN * 2;   // 6400064
    const size_t cb_bytes  = (size_t)N_VOX * C_OUT * 2;        // 12800000
    const size_t pt_bytes  = (size_t)128 * NB_FB * 4;          // 400384 (covers both)

    const bool bf_ok = ws_size >= wt_bytes + fb_bytes + pt_bytes + 1024;
    const bool cb_ok = ws_size >= wt_bytes + fb_bytes + cb_bytes + pt_bytes + 1024;

    unsigned short* Wt = (unsigned short*)ws;
    unsigned short* feat_bf = (unsigned short*)(ws + wt_bytes);
    unsigned short* cbf = (unsigned short*)(ws + wt_bytes + fb_bytes);
    float* partials;
    if (cb_ok)       partials = (float*)(ws + wt_bytes + fb_bytes + cb_bytes);
    else if (bf_ok)  partials = (float*)(ws + wt_bytes + fb_bytes);
    else             partials = (float*)(ws + wt_bytes);
    float* ss = partials + 128 * NB_FB;

    if (bf_ok) {
        int feat_blocks = (((N_VOX + 1) * C_IN) / 8 + 255) / 256;  // 1563
        prep_kernel<<<WT_BLOCKS + feat_blocks, 256, 0, stream>>>(W, Wt, feat, feat_bf);
        if (cb_ok)
            conv_kernel<true><<<GRID_C, CONV_T, 0, stream>>>(
                feat_bf, nidx, Wt, out, cbf, partials);
        else
            conv_kernel<false><<<GRID_C, CONV_T, 0, stream>>>(
                feat_bf, nidx, Wt, out, cbf, partials);
        stats_kernel<<<C_OUT, 256, 0, stream>>>(partials, GRID_C, gamma, beta, ss);
    } else {
        prep_kernel<<<WT_BLOCKS, 256, 0, stream>>>(W, Wt, feat, Wt);
        conv_fb_kernel<<<NB_FB, 512, 0, stream>>>(feat, nidx, Wt, out, partials);
        stats_kernel<<<C_OUT, 256, 0, stream>>>(partials, NB_FB, gamma, beta, ss);
    }
    if (cb_ok)
        bn_relu_b_kernel<<<N_VOX * C_OUT / 8 / 256, 256, 0, stream>>>(cbf, ss, out);
    else
        bn_relu_f_kernel<<<N_VOX * C_OUT / 4 / 256, 256, 0, stream>>>(out, ss);
}

// Round 21
// 39.000 us; speedup vs baseline: 1.0458x; 1.0030x over previous
//
#include <hip/hip_runtime.h>
#include <hip/hip_bf16.h>

#define N_VOX 100000
#define C_IN  32
#define C_OUT 64
#define KOFF  27
#define CONV_T 1024            // 16 waves: 4/SIMD at 1 block/CU
#define GRID_C 256             // all CUs; tiles block-strided across blocks
#define NTILES 3125            // 100000/32 exactly (per-wave 32-voxel tiles)
#define NB_FB  782             // fallback tiles
#define WT_BLOCKS 216          // 27*64*32 / 256
#define WT_HALFS (KOFF * C_OUT * C_IN)   // 55296 bf16
#define WT_BYTES (WT_HALFS * 2)          // 110592 B

typedef __attribute__((ext_vector_type(8))) short bf16x8_t;
typedef __attribute__((ext_vector_type(4))) float f32x4_t;

__device__ __forceinline__ short f2bf(float f) {
    __hip_bfloat16 h = __float2bfloat16(f);
    return __builtin_bit_cast(short, h);
}
__device__ __forceinline__ float bf2f(unsigned short u) {
    return __builtin_bit_cast(float, (unsigned)u << 16);
}

// prep: blocks [0,216): Wt PRE-SWIZZLED: element (k,d,c) -> linear index
// (k<<11|d<<5|c) ^ ((d&7)<<3); linear copy to LDS preserves the bank swizzle.
// blocks [216,...): features f32 -> bf16 (+ zero row at N_VOX)
__global__ void prep_kernel(const float* __restrict__ W,
                            unsigned short* __restrict__ Wt,
                            const float* __restrict__ feat,
                            unsigned short* __restrict__ fb) {
    int bid = blockIdx.x;
    if (bid < WT_BLOCKS) {
        int i = bid * 256 + threadIdx.x;   // exactly 55296
        int c = i & 31;
        int d = (i >> 5) & 63;
        int k = i >> 11;
        int dst = i ^ ((d & 7) << 3);
        Wt[dst] = (unsigned short)f2bf(W[k * (C_IN * C_OUT) + c * C_OUT + d]);
    } else {
        int t = (bid - WT_BLOCKS) * 256 + threadIdx.x;
        const int total8 = ((N_VOX + 1) * C_IN) / 8;    // 400004
        if (t >= total8) return;
        int e = t * 8;
        bf16x8_t o;
        if (e < N_VOX * C_IN) {
            const f32x4_t* fp = (const f32x4_t*)(feat + e);
            f32x4_t f0 = fp[0], f1 = fp[1];
            o[0] = f2bf(f0[0]); o[1] = f2bf(f0[1]); o[2] = f2bf(f0[2]); o[3] = f2bf(f0[3]);
            o[4] = f2bf(f1[0]); o[5] = f2bf(f1[1]); o[6] = f2bf(f1[2]); o[7] = f2bf(f1[3]);
        } else {
            o = (bf16x8_t)(short)0;
        }
        *(bf16x8_t*)(fb + e) = o;
    }
}

#define GLOAD(dst, voff)                                                      \
    asm volatile("global_load_dwordx4 %0, %1, %2"                             \
                 : "=v"(dst) : "v"(voff), "s"(feat_bf))

#define VMW(n) do {                                                           \
    asm volatile("s_waitcnt vmcnt(" #n ")" ::: "memory");                     \
    __builtin_amdgcn_sched_barrier(0);                                        \
} while (0)

template <bool OUTBF>
__global__ __attribute__((amdgpu_flat_work_group_size(CONV_T, CONV_T),
                          amdgpu_waves_per_eu(4, 4)))
void conv_kernel(
    const unsigned short* __restrict__ feat_bf,
    const int* __restrict__ nidx,
    const unsigned short* __restrict__ WtG,
    float* __restrict__ outf, unsigned short* __restrict__ outb,
    float* __restrict__ partials)
{
    __shared__ unsigned short wt_lds[WT_HALFS];   // 110592 B, swizzle pre-baked
    __shared__ float lsum[16][C_OUT];
    __shared__ float lsq[16][C_OUT];

    const int tid  = threadIdx.x;
    const int wid  = tid >> 6;
    const int lane = tid & 63;
    const int colr = lane & 15;
    const int kch  = lane >> 4;

    // stage weights once per block
    for (int j = tid; j < WT_HALFS / 8; j += CONV_T)
        ((bf16x8_t*)wt_lds)[j] = ((const bf16x8_t*)WtG)[j];
    __syncthreads();

    const int b = blockIdx.x;
    // block-strided per-wave tile id: every CU gets ~12.2 active waves
    const int g = wid * GRID_C + b;
    const bool active = (g < NTILES);
    const int base = g * 32;

    float psum[4] = {0.f, 0.f, 0.f, 0.f};
    float psq[4]  = {0.f, 0.f, 0.f, 0.f};

    if (active) {
        // phase 0: 54 gather byte-offsets (compiler nidx VMEM drains here;
        // the staging __syncthreads drained vmcnt -> counting starts clean)
        unsigned off[54];
        #pragma unroll
        for (int m = 0; m < 2; ++m) {
            int vx = base + m * 16 + colr;
            bool val = vx < N_VOX;
            const int* nr = nidx + (val ? vx : 0) * KOFF;
            int force = val ? 0 : -1;
            #pragma unroll
            for (int k = 0; k < KOFF; ++k) {
                int id = nr[k] | force;
                int s = (id < 0) ? N_VOX : id;    // zero row for invalid
                off[k * 2 + m] = ((unsigned)s << 6) + (unsigned)(kch << 4);
            }
        }
        __builtin_amdgcn_sched_barrier(0);

        f32x4_t acc0[4], acc1[4];
        #pragma unroll
        for (int t = 0; t < 4; ++t) { acc0[t] = (f32x4_t)0.0f; acc1[t] = (f32x4_t)0.0f; }

        // 2-chunk-deep burst: 12 fragments live (round-13-proven ping-pong)
        bf16x8_t a[12];
        #pragma unroll
        for (int u = 0; u < 12; ++u) GLOAD(a[u], off[u]);
        __builtin_amdgcn_sched_barrier(0);

        // 9 chunks of 3 k-offsets; each b-read feeds TWO MFMAs (M=32).
        // T5: independent out-of-phase waves -> setprio(1) around the MFMA
        // cluster lets the CU scheduler favor compute-ready waves (m191 regime)
        #pragma unroll
        for (int c = 0; c < 9; ++c) {
            if (c < 8) { VMW(6); } else { VMW(0); }
            const int ab = (c & 1) * 6;
            __builtin_amdgcn_s_setprio(1);
            #pragma unroll
            for (int j = 0; j < 3; ++j) {
                const int kk = c * 3 + j;
                #pragma unroll
                for (int t = 0; t < 4; ++t) {
                    const int rw = t * 16 + colr;
                    int o = (kk << 12) + (rw << 6) + (kch << 4);
                    o ^= (rw & 7) << 4;
                    bf16x8_t bb = *(const bf16x8_t*)((const char*)wt_lds + o);
                    acc0[t] = __builtin_amdgcn_mfma_f32_16x16x32_bf16(
                        a[ab + j * 2 + 0], bb, acc0[t], 0, 0, 0);
                    acc1[t] = __builtin_amdgcn_mfma_f32_16x16x32_bf16(
                        a[ab + j * 2 + 1], bb, acc1[t], 0, 0, 0);
                }
            }
            __builtin_amdgcn_s_setprio(0);
            if (c + 2 < 9) {
                const int nb2 = ((c + 2) & 1) * 6;
                #pragma unroll
                for (int u = 0; u < 6; ++u) GLOAD(a[nb2 + u], off[(c + 2) * 6 + u]);
                __builtin_amdgcn_sched_barrier(0);
            }
        }

        // epilogue: C/D col = lane&15 (channel), row = kch*4+i (voxel)
        #pragma unroll
        for (int t = 0; t < 4; ++t) {
            #pragma unroll
            for (int i = 0; i < 4; ++i) {
                int v0 = base + kch * 4 + i;
                int v1 = v0 + 16;
                int ch = t * 16 + colr;
                float x0 = acc0[t][i], x1 = acc1[t][i];
                if (v0 < N_VOX) {
                    if constexpr (OUTBF) outb[v0 * C_OUT + ch] = (unsigned short)f2bf(x0);
                    else                 outf[v0 * C_OUT + ch] = x0;
                }
                if (v1 < N_VOX) {
                    if constexpr (OUTBF) outb[v1 * C_OUT + ch] = (unsigned short)f2bf(x1);
                    else                 outf[v1 * C_OUT + ch] = x1;
                }
                psum[t] += x0 + x1;
                psq[t]  += x0 * x0 + x1 * x1;
            }
        }
    }

    #pragma unroll
    for (int t = 0; t < 4; ++t) {
        psum[t] += __shfl_xor(psum[t], 16);
        psum[t] += __shfl_xor(psum[t], 32);
        psq[t]  += __shfl_xor(psq[t], 16);
        psq[t]  += __shfl_xor(psq[t], 32);
    }
    if (lane < 16) {
        #pragma unroll
        for (int t = 0; t < 4; ++t) {
            lsum[wid][t * 16 + lane] = psum[t];
            lsq[wid][t * 16 + lane]  = psq[t];
        }
    }
    __syncthreads();
    if (tid < 128) {
        int c = tid & 63;
        float s = 0.f;
        if (tid < 64) {
            #pragma unroll
            for (int w = 0; w < 16; ++w) s += lsum[w][c];
        } else {
            #pragma unroll
            for (int w = 0; w < 16; ++w) s += lsq[w][c];
        }
        partials[tid * GRID_C + b] = s;
    }
}

// fallback (tiny ws): f32 gather, shallow loop, M=16, non-persistent
__global__ __launch_bounds__(512) void conv_fb_kernel(
    const float* __restrict__ feat,
    const int* __restrict__ nidx,
    const unsigned short* __restrict__ WtG,
    float* __restrict__ outf, float* __restrict__ partials)
{
    __shared__ unsigned short wt_lds[WT_HALFS];
    __shared__ float lsum[8][C_OUT];
    __shared__ float lsq[8][C_OUT];

    const int tid  = threadIdx.x;
    const int wid  = tid >> 6;
    const int lane = tid & 63;
    const int colr = lane & 15;
    const int kch  = lane >> 4;
    const int base = blockIdx.x * 128 + wid * 16;
    const int vox  = base + colr;
    const bool valid = (vox < N_VOX);
    const int* nrow = nidx + (valid ? vox : 0) * KOFF;

    for (int j = tid; j < WT_HALFS / 8; j += 512)
        ((bf16x8_t*)wt_lds)[j] = ((const bf16x8_t*)WtG)[j];
    __syncthreads();

    f32x4_t acc[4];
    #pragma unroll
    for (int t = 0; t < 4; ++t) acc[t] = (f32x4_t)0.0f;

    for (int k = 0; k < KOFF; ++k) {
        int idx = valid ? nrow[k] : -1;
        bf16x8_t av = (bf16x8_t)(short)0;
        if (idx >= 0) {
            const f32x4_t* fp = (const f32x4_t*)(feat + (idx << 5) + kch * 8);
            f32x4_t f0 = fp[0], f1 = fp[1];
            av[0] = f2bf(f0[0]); av[1] = f2bf(f0[1]);
            av[2] = f2bf(f0[2]); av[3] = f2bf(f0[3]);
            av[4] = f2bf(f1[0]); av[5] = f2bf(f1[1]);
            av[6] = f2bf(f1[2]); av[7] = f2bf(f1[3]);
        }
        #pragma unroll
        for (int t = 0; t < 4; ++t) {
            int rw = t * 16 + colr;
            int o = (k << 12) + (rw << 6) + (kch << 4);
            o ^= (rw & 7) << 4;
            bf16x8_t bb = *(const bf16x8_t*)((const char*)wt_lds + o);
            acc[t] = __builtin_amdgcn_mfma_f32_16x16x32_bf16(av, bb, acc[t], 0, 0, 0);
        }
    }

    float psum[4], psq[4];
    #pragma unroll
    for (int t = 0; t < 4; ++t) { psum[t] = 0.f; psq[t] = 0.f; }
    #pragma unroll
    for (int t = 0; t < 4; ++t) {
        #pragma unroll
        for (int i = 0; i < 4; ++i) {
            int v = base + kch * 4 + i;
            float x = acc[t][i];
            if (v < N_VOX) outf[v * C_OUT + t * 16 + colr] = x;
            psum[t] += x;
            psq[t]  += x * x;
        }
    }
    #pragma unroll
    for (int t = 0; t < 4; ++t) {
        psum[t] += __shfl_xor(psum[t], 16);
        psum[t] += __shfl_xor(psum[t], 32);
        psq[t]  += __shfl_xor(psq[t], 16);
        psq[t]  += __shfl_xor(psq[t], 32);
    }
    if (lane < 16) {
        #pragma unroll
        for (int t = 0; t < 4; ++t) {
            lsum[wid][t * 16 + lane] = psum[t];
            lsq[wid][t * 16 + lane]  = psq[t];
        }
    }
    __syncthreads();
    if (tid < 128) {
        int c = tid & 63;
        float s = 0.f;
        if (tid < 64) {
            #pragma unroll
            for (int w = 0; w < 8; ++w) s += lsum[w][c];
        } else {
            #pragma unroll
            for (int w = 0; w < 8; ++w) s += lsq[w][c];
        }
        partials[tid * NB_FB + blockIdx.x] = s;
    }
}

__global__ __launch_bounds__(256) void stats_kernel(
    const float* __restrict__ partials, int nb,
    const float* __restrict__ gamma, const float* __restrict__ beta,
    float* __restrict__ ss)
{
    __shared__ float bs[4], bq[4];
    const int c = blockIdx.x;
    const float* ps = partials + c * nb;
    const float* pq = partials + (64 + c) * nb;
    float s = 0.f, q = 0.f;
    for (int i = threadIdx.x; i < nb; i += 256) {
        s += ps[i];
        q += pq[i];
    }
    #pragma unroll
    for (int o = 1; o < 64; o <<= 1) {
        s += __shfl_xor(s, o);
        q += __shfl_xor(q, o);
    }
    int wid = threadIdx.x >> 6, lane = threadIdx.x & 63;
    if (lane == 0) { bs[wid] = s; bq[wid] = q; }
    __syncthreads();
    if (threadIdx.x == 0) {
        float S = bs[0] + bs[1] + bs[2] + bs[3];
        float Q = bq[0] + bq[1] + bq[2] + bq[3];
        float mean = S * (1.0f / N_VOX);
        float var  = Q * (1.0f / N_VOX) - mean * mean;
        float inv  = rsqrtf(var + 1e-5f);
        float sc   = gamma[c] * inv;
        ss[c]      = sc;
        ss[64 + c] = beta[c] - mean * sc;
    }
}

// bf16 intermediate -> f32 output
__global__ void bn_relu_b_kernel(const unsigned short* __restrict__ cbf,
                                 const float* __restrict__ ss,
                                 float* __restrict__ out) {
    int i = blockIdx.x * 256 + threadIdx.x;   // exactly N*64/8 threads
    bf16x8_t v = ((const bf16x8_t*)cbf)[i];
    int d0 = (i * 8) & 63;
    f32x4_t sc0 = *(const f32x4_t*)(ss + d0);
    f32x4_t sc1 = *(const f32x4_t*)(ss + d0 + 4);
    f32x4_t sh0 = *(const f32x4_t*)(ss + 64 + d0);
    f32x4_t sh1 = *(const f32x4_t*)(ss + 64 + d0 + 4);
    f32x4_t o0, o1;
    #pragma unroll
    for (int j = 0; j < 4; ++j) {
        o0[j] = fmaxf(bf2f((unsigned short)v[j]) * sc0[j] + sh0[j], 0.f);
        o1[j] = fmaxf(bf2f((unsigned short)v[j + 4]) * sc1[j] + sh1[j], 0.f);
    }
    ((f32x4_t*)out)[2 * i]     = o0;
    ((f32x4_t*)out)[2 * i + 1] = o1;
}

// f32 in-place
__global__ void bn_relu_f_kernel(float* __restrict__ out,
                                 const float* __restrict__ ss) {
    int i = blockIdx.x * 256 + threadIdx.x;  // exactly N*64/4 threads
    f32x4_t v = ((f32x4_t*)out)[i];
    int d0 = (i * 4) & 63;
    f32x4_t sc = *(const f32x4_t*)(ss + d0);
    f32x4_t sh = *(const f32x4_t*)(ss + 64 + d0);
    #pragma unroll
    for (int j = 0; j < 4; ++j) v[j] = fmaxf(v[j] * sc[j] + sh[j], 0.f);
    ((f32x4_t*)out)[i] = v;
}

extern "C" void kernel_launch(void* const* d_in, const int* in_sizes, int n_in,
                              void* d_out, int out_size, void* d_ws, size_t ws_size,
                              hipStream_t stream) {
    const float* feat  = (const float*)d_in[0];
    const int*   nidx  = (const int*)d_in[1];
    const float* W     = (const float*)d_in[2];
    const float* gamma = (const float*)d_in[3];
    const float* beta  = (const float*)d_in[4];
    float* out = (float*)d_out;

    char* ws = (char*)d_ws;
    const size_t wt_bytes  = WT_BYTES;                         // 110592
    const size_t fb_bytes  = (size_t)(N_VOX + 1) * C_IN * 2;   // 6400064
    const size_t cb_bytes  = (size_t)N_VOX * C_OUT * 2;        // 12800000
    const size_t pt_bytes  = (size_t)128 * NB_FB * 4;          // 400384 (covers both)

    const bool bf_ok = ws_size >= wt_bytes + fb_bytes + pt_bytes + 1024;
    const bool cb_ok = ws_size >= wt_bytes + fb_bytes + cb_bytes + pt_bytes + 1024;

    unsigned short* Wt = (unsigned short*)ws;
    unsigned short* feat_bf = (unsigned short*)(ws + wt_bytes);
    unsigned short* cbf = (unsigned short*)(ws + wt_bytes + fb_bytes);
    float* partials;
    if (cb_ok)       partials = (float*)(ws + wt_bytes + fb_bytes + cb_bytes);
    else if (bf_ok)  partials = (float*)(ws + wt_bytes + fb_bytes);
    else             partials = (float*)(ws + wt_bytes);
    float* ss = partials + 128 * NB_FB;

    if (bf_ok) {
        int feat_blocks = (((N_VOX + 1) * C_IN) / 8 + 255) / 256;  // 1563
        prep_kernel<<<WT_BLOCKS + feat_blocks, 256, 0, stream>>>(W, Wt, feat, feat_bf);
        if (cb_ok)
            conv_kernel<true><<<GRID_C, CONV_T, 0, stream>>>(
                feat_bf, nidx, Wt, out, cbf, partials);
        else
            conv_kernel<false><<<GRID_C, CONV_T, 0, stream>>>(
                feat_bf, nidx, Wt, out, cbf, partials);
        stats_kernel<<<C_OUT, 256, 0, stream>>>(partials, GRID_C, gamma, beta, ss);
    } else {
        prep_kernel<<<WT_BLOCKS, 256, 0, stream>>>(W, Wt, feat, Wt);
        conv_fb_kernel<<<NB_FB, 512, 0, stream>>>(feat, nidx, Wt, out, partials);
        stats_kernel<<<C_OUT, 256, 0, stream>>>(partials, NB_FB, gamma, beta, ss);
    }
    if (cb_ok)
        bn_relu_b_kernel<<<N_VOX * C_OUT / 8 / 256, 256, 0, stream>>>(cbf, ss, out);
    else
        bn_relu_f_kernel<<<N_VOX * C_OUT / 4 / 256, 256, 0, stream>>>(out, ss);
}